// Round 15
// baseline (105.227 us; speedup 1.0000x reference)
//
#include <hip/hip_runtime.h>
#include <hip/hip_fp16.h>
#include <math.h>

#define NB 64    // batches
#define NN 512   // sequence length
#define NE 12    // embed dim
#define NH 4     // heads
#define NF 13    // features (F-3)

typedef __attribute__((ext_vector_type(4))) _Float16 f16x4;
typedef __attribute__((ext_vector_type(4))) float    f32x4;

__device__ inline float wave_reduce_add(float v) {
#pragma unroll
    for (int off = 1; off < 64; off <<= 1) v += __shfl_xor(v, off);
    return v;
}

__device__ inline unsigned h2u(__half2 h) { union { __half2 h; unsigned u; } c; c.h = h; return c.u; }

union HU { f16x4 h; uint2 u; };

// ---------------------------------------------------------------------------
// prep: center coords, compute y_translate, project coords->E and feats->E
// ---------------------------------------------------------------------------
__global__ __launch_bounds__(512) void prep_kernel(
    const float* __restrict__ x_orig, const float* __restrict__ y_orig,
    const float* __restrict__ lin_in_w, const float* __restrict__ lin_in_b,
    const float* __restrict__ lin_coords_w, const float* __restrict__ lin_coords_b,
    float* __restrict__ x_c, float* __restrict__ y_tr,
    float* __restrict__ xi, float* __restrict__ yi,
    float* __restrict__ xi_feat, float* __restrict__ yi_feat)
{
    const int b = blockIdx.x;
    const int n = threadIdx.x;
    const size_t row = (size_t)b * NN + n;
    const float* xr = x_orig + row * 16;
    const float* yr = y_orig + row * 16;
    float xv[16], yv[16];
#pragma unroll
    for (int i = 0; i < 16; ++i) { xv[i] = xr[i]; yv[i] = yr[i]; }

    __shared__ float part[8][6];
    const int wid = n >> 6, lane = n & 63;
    float r0 = wave_reduce_add(xv[0]);
    float r1 = wave_reduce_add(xv[1]);
    float r2 = wave_reduce_add(xv[2]);
    float r3 = wave_reduce_add(yv[0]);
    float r4 = wave_reduce_add(yv[1]);
    float r5 = wave_reduce_add(yv[2]);
    if (lane == 0) {
        part[wid][0] = r0; part[wid][1] = r1; part[wid][2] = r2;
        part[wid][3] = r3; part[wid][4] = r4; part[wid][5] = r5;
    }
    __syncthreads();
    float xm[3], ym[3];
#pragma unroll
    for (int c = 0; c < 3; ++c) {
        float sx = 0.f, sy = 0.f;
#pragma unroll
        for (int w = 0; w < 8; ++w) { sx += part[w][c]; sy += part[w][3 + c]; }
        xm[c] = sx * (1.0f / NN); ym[c] = sy * (1.0f / NN);
    }

    float xc[3], yc[3];
#pragma unroll
    for (int c = 0; c < 3; ++c) { xc[c] = xv[c] - xm[c]; yc[c] = yv[c] - ym[c]; }

#pragma unroll
    for (int c = 0; c < 3; ++c) x_c[row * 3 + c] = xc[c];
    if (n < 3) y_tr[b * 3 + n] = ym[n];

#pragma unroll
    for (int e = 0; e < NE; ++e) {
        float sx = lin_coords_b[e], sy = lin_coords_b[e];
#pragma unroll
        for (int c = 0; c < 3; ++c) {
            sx += xc[c] * lin_coords_w[e * 3 + c];
            sy += yc[c] * lin_coords_w[e * 3 + c];
        }
        xi[row * NE + e] = sx;
        yi[row * NE + e] = sy;
    }
#pragma unroll
    for (int e = 0; e < NE; ++e) {
        float sx = lin_in_b[e], sy = lin_in_b[e];
#pragma unroll
        for (int f = 0; f < NF; ++f) {
            sx += xv[3 + f] * lin_in_w[e * NF + f];
            sy += yv[3 + f] * lin_in_w[e * NF + f];
        }
        xi_feat[row * NE + e] = sx;
        yi_feat[row * NE + e] = sy;
    }
}

// ---------------------------------------------------------------------------
// MFMA fused MHA (batched over up to 4 independent ops per dispatch)
// r15: per op 512 blocks = (b, 64-query eighth); 512 threads = 8 waves.
// wave w: head h = w>>1, 32-q half q32 = w&1, owns 2 q-tiles of 16.
// Per-wave live state qf(4)+acc(8)+s(8)+addr ~ 28 regs -- fits the 40-VGPR
// allocation WITHOUT remat/serialization [r13/r14: 4-q-tile version needed
// >40 live and got chain-serialized; allocator refuses more than 40].
// Also doubles per-op grid: batch-3 256->512 blocks (33%->67% capacity),
// batch-1 tail round 33%->67% occupied.
// S-tile = mfma_16x16x16_f16(A=K, B=Q) -> exp2 in-register -> fragment
// feeds PV mfma(A=V^T, B=P) directly (D layout == B-operand layout,
// HW-verified r10). V^T row 3 = ones -> denominator in acc row 3.
// ---------------------------------------------------------------------------
struct MhaBatchArgs {
    const float* q[4];
    const float* kv[4];
    const float* wi[4];
    const float* bi[4];
    const float* wo[4];
    const float* bo[4];
    float*       out[4];
};

__global__ __launch_bounds__(512) void attn_mfma_kernel(MhaBatchArgs args)
{
    const int op    = blockIdx.x >> 9;
    const int bid   = blockIdx.x & 511;
    const int b     = bid >> 3;
    const int qbase = (bid & 7) << 6;    // eighth * 64
    const int tid   = threadIdx.x;
    const int lane  = tid & 63;
    const int w     = tid >> 6;
    const int h     = w >> 1;            // head
    const int q32   = w & 1;             // which 32-q half of the 64

    const float* __restrict__ qin   = args.q[op];
    const float* __restrict__ kvin  = args.kv[op];
    const float* __restrict__ w_in  = args.wi[op];
    const float* __restrict__ b_in  = args.bi[op];
    const float* __restrict__ w_out = args.wo[op];
    const float* __restrict__ b_out = args.bo[op];
    float* __restrict__ out = args.out[op];

    __shared__ __align__(16) __half K_lds[NH][NN][4];   // (kx,ky,kz,0) 16,384 B
    __shared__ __align__(16) __half V_lds[NH][4][528];  // rows vx,vy,vz,1 16,896 B
    __shared__ __align__(16) uint2  qbuf[64][NH];       // Q f16 staging 2,048 B
    __shared__ __align__(16) float  att[64][NE];        // 3,072 B
    __shared__ float  w_lds[36][NE];
    __shared__ float  b_lds[36];
    __shared__ __align__(16) float4 wo4[NE][3];
    __shared__ float  bo_lds[NE];

    if (tid < 432) w_lds[tid / NE][tid % NE] = w_in[tid];
    if (tid < 36)  b_lds[tid] = b_in[tid];
    if (tid < 144) ((float*)wo4)[tid] = w_out[tid];
    if (tid < NE)  bo_lds[tid] = b_out[tid];
    __syncthreads();

    // ---- stage K,V (thread = key, all heads), f16 ----
    {
        const int n = tid;
        const float4* kvrow = (const float4*)(kvin + ((size_t)b * NN + n) * NE);
        float4 r0 = kvrow[0], r1 = kvrow[1], r2 = kvrow[2];
        float x[NE] = { r0.x, r0.y, r0.z, r0.w, r1.x, r1.y, r1.z, r1.w,
                        r2.x, r2.y, r2.z, r2.w };
#pragma unroll
        for (int hh = 0; hh < NH; ++hh) {
            float sk[3], sv[3];
#pragma unroll
            for (int c = 0; c < 3; ++c) {
                const int rk = NE + hh * 3 + c;
                const int rv = 2 * NE + hh * 3 + c;
                float a = b_lds[rk], v = b_lds[rv];
#pragma unroll
                for (int e = 0; e < NE; ++e) {
                    a += x[e] * w_lds[rk][e];
                    v += x[e] * w_lds[rv][e];
                }
                sk[c] = a; sv[c] = v;
            }
            uint2 kk;
            kk.x = h2u(__floats2half2_rn(sk[0], sk[1]));
            kk.y = h2u(__floats2half2_rn(sk[2], 0.0f));
            *(uint2*)&K_lds[hh][n][0] = kk;
            V_lds[hh][0][n] = __float2half(sv[0]);
            V_lds[hh][1][n] = __float2half(sv[1]);
            V_lds[hh][2][n] = __float2half(sv[2]);
            V_lds[hh][3][n] = __float2half(1.0f);
        }
    }
    // ---- stage Q (thread = (q, head), 256 threads); scale folded ----
    if (tid < 256) {
        const float scale = 0.83294037f;   // log2(e)/sqrt(3)
        const int q = tid >> 2, hh = tid & 3;
        const float4* qrow = (const float4*)(qin + ((size_t)b * NN + qbase + q) * NE);
        float4 r0 = qrow[0], r1 = qrow[1], r2 = qrow[2];
        float x[NE] = { r0.x, r0.y, r0.z, r0.w, r1.x, r1.y, r1.z, r1.w,
                        r2.x, r2.y, r2.z, r2.w };
        float qc[3];
#pragma unroll
        for (int c = 0; c < 3; ++c) {
            const int rq = hh * 3 + c;
            float s = b_lds[rq];
#pragma unroll
            for (int e = 0; e < NE; ++e) s += x[e] * w_lds[rq][e];
            qc[c] = s * scale;
        }
        uint2 qq;
        qq.x = h2u(__floats2half2_rn(qc[0], qc[1]));
        qq.y = h2u(__floats2half2_rn(qc[2], 0.0f));
        qbuf[q][hh] = qq;
    }
    __syncthreads();

    // ---- per-wave Q B-fragments (2 q-tiles); rows d>=3 MUST be zero ----
    const int ql = lane & 15;
    const int g  = lane >> 4;
    f16x4 qf0, qf1;
    {
        HU c0, c1;
        c0.u = qbuf[q32 * 32 +  0 + ql][h];
        c1.u = qbuf[q32 * 32 + 16 + ql][h];
        if (lane >= 16) { c0.u.x = 0u; c0.u.y = 0u; c1.u.x = 0u; c1.u.y = 0u; }
        qf0 = c0.h; qf1 = c1.h;
    }
    f32x4 acc0 = {0.f,0.f,0.f,0.f}, acc1 = {0.f,0.f,0.f,0.f};
    const f32x4 zero4 = {0.f, 0.f, 0.f, 0.f};
    const int vrow = lane & 3;
    const int voff = 4 * g;

    // ---- main loop: 32 k-tiles of 16 keys (r13 loop form, 2 q-tiles) ----
#pragma unroll 2
    for (int ks = 0; ks < 32; ++ks) {
        HU kc; kc.u = *(const uint2*)&K_lds[h][ks * 16 + ql][0];
        HU vc; vc.u = *(const uint2*)&V_lds[h][vrow][ks * 16 + voff];
        {
            f32x4 s = __builtin_amdgcn_mfma_f32_16x16x16f16(kc.h, qf0, zero4, 0, 0, 0);
            HU pc;
            pc.u.x = h2u(__floats2half2_rn(__builtin_amdgcn_exp2f(s[0]),
                                           __builtin_amdgcn_exp2f(s[1])));
            pc.u.y = h2u(__floats2half2_rn(__builtin_amdgcn_exp2f(s[2]),
                                           __builtin_amdgcn_exp2f(s[3])));
            acc0 = __builtin_amdgcn_mfma_f32_16x16x16f16(vc.h, pc.h, acc0, 0, 0, 0);
        }
        {
            f32x4 s = __builtin_amdgcn_mfma_f32_16x16x16f16(kc.h, qf1, zero4, 0, 0, 0);
            HU pc;
            pc.u.x = h2u(__floats2half2_rn(__builtin_amdgcn_exp2f(s[0]),
                                           __builtin_amdgcn_exp2f(s[1])));
            pc.u.y = h2u(__floats2half2_rn(__builtin_amdgcn_exp2f(s[2]),
                                           __builtin_amdgcn_exp2f(s[3])));
            acc1 = __builtin_amdgcn_mfma_f32_16x16x16f16(vc.h, pc.h, acc1, 0, 0, 0);
        }
    }

    // ---- epilogue: lanes 0-15 hold rows 0-3 = (o0,o1,o2,l) per q ----
    if (lane < 16) {
        const int qloc = q32 * 32 + lane;
        {
            const float inv = 1.0f / acc0[3];
            att[qloc +  0][h * 3 + 0] = acc0[0] * inv;
            att[qloc +  0][h * 3 + 1] = acc0[1] * inv;
            att[qloc +  0][h * 3 + 2] = acc0[2] * inv;
        }
        {
            const float inv = 1.0f / acc1[3];
            att[qloc + 16][h * 3 + 0] = acc1[0] * inv;
            att[qloc + 16][h * 3 + 1] = acc1[1] * inv;
            att[qloc + 16][h * 3 + 2] = acc1[2] * inv;
        }
    }
    __syncthreads();

    // ---- fused output projection: 64 q x 12 outputs ----
    for (int idx = tid; idx < 64 * NE; idx += 512) {
        const int qq = idx / NE, o = idx % NE;
        const float4* a4 = (const float4*)&att[qq][0];
        float4 a0 = a4[0], a1 = a4[1], a2 = a4[2];
        float4 w0 = wo4[o][0], w1 = wo4[o][1], w2 = wo4[o][2];
        float s = bo_lds[o]
                + a0.x * w0.x + a0.y * w0.y + a0.z * w0.z + a0.w * w0.w
                + a1.x * w1.x + a1.y * w1.y + a1.z * w1.z + a1.w * w1.w
                + a2.x * w2.x + a2.y * w2.y + a2.z * w2.z + a2.w * w2.w;
        out[((size_t)b * NN + qbase + qq) * NE + o] = s;
    }
}

// ---------------------------------------------------------------------------
// fused kabsch: coords-proj + stats reduce + Newton polar solve + final
// transform, one kernel, one block per batch.
// ---------------------------------------------------------------------------
__global__ __launch_bounds__(512) void kabsch_fused_kernel(
    const float* __restrict__ cross, const float* __restrict__ lin_out_w,
    const float* __restrict__ lin_out_b, const float* __restrict__ x_c,
    const float* __restrict__ y_tr, float* __restrict__ out)
{
    const int b = blockIdx.x;
    const int n = threadIdx.x;
    const size_t row = (size_t)b * NN + n;
    const float* xr = cross + row * NE;
    float xin[NE];
#pragma unroll
    for (int e = 0; e < NE; ++e) xin[e] = xr[e];
    float cd[3];
#pragma unroll
    for (int o = 0; o < 3; ++o) {
        float s = lin_out_b[o];
#pragma unroll
        for (int e = 0; e < NE; ++e) s += xin[e] * lin_out_w[o * NE + e];
        cd[o] = s;
    }
    float Bx[3], A[3];
#pragma unroll
    for (int c = 0; c < 3; ++c) { Bx[c] = x_c[row * 3 + c]; A[c] = cd[c] + Bx[c]; }

    float vals[15];
#pragma unroll
    for (int i = 0; i < 3; ++i)
#pragma unroll
        for (int j = 0; j < 3; ++j) vals[i * 3 + j] = Bx[i] * A[j];
#pragma unroll
    for (int i = 0; i < 3; ++i) { vals[9 + i] = Bx[i]; vals[12 + i] = A[i]; }

    __shared__ float part[8][15];
    __shared__ float Rt[12];           // R[9], t[3] (t includes y_tr)
    const int wid = n >> 6, lane = n & 63;
#pragma unroll
    for (int t = 0; t < 15; ++t) {
        float r = wave_reduce_add(vals[t]);
        if (lane == 0) part[wid][t] = r;
    }
    __syncthreads();

    if (n == 0) {
        float s[15];
#pragma unroll
        for (int t = 0; t < 15; ++t) {
            float acc = 0.f;
#pragma unroll
            for (int ww = 0; ww < 8; ++ww) acc += part[ww][t];
            s[t] = acc;
        }
        float cB[3], cA[3];
#pragma unroll
        for (int j = 0; j < 3; ++j) { cB[j] = s[9 + j] * (1.0f / NN); cA[j] = s[12 + j] * (1.0f / NN); }
        float X[3][3];
#pragma unroll
        for (int i = 0; i < 3; ++i)
#pragma unroll
            for (int j = 0; j < 3; ++j) X[i][j] = s[i * 3 + j] - s[9 + i] * cA[j];

        for (int it = 0; it < 14; ++it) {
            float c00 =  X[1][1] * X[2][2] - X[1][2] * X[2][1];
            float c01 = -(X[1][0] * X[2][2] - X[1][2] * X[2][0]);
            float c02 =  X[1][0] * X[2][1] - X[1][1] * X[2][0];
            float c10 = -(X[0][1] * X[2][2] - X[0][2] * X[2][1]);
            float c11 =  X[0][0] * X[2][2] - X[0][2] * X[2][0];
            float c12 = -(X[0][0] * X[2][1] - X[0][1] * X[2][0]);
            float c20 =  X[0][1] * X[1][2] - X[0][2] * X[1][1];
            float c21 = -(X[0][0] * X[1][2] - X[0][2] * X[1][0]);
            float c22 =  X[0][0] * X[1][1] - X[0][1] * X[1][0];
            float det = X[0][0] * c00 + X[0][1] * c01 + X[0][2] * c02;
            float ad = fabsf(det);
            float g  = (ad > 1e-30f) ? 1.0f / cbrtf(ad) : 1.0f;
            float hg  = 0.5f * g;
            float hgi = 0.5f / (g * det);
            float Xn[3][3];
            Xn[0][0] = hg * X[0][0] + hgi * c00;
            Xn[0][1] = hg * X[0][1] + hgi * c01;
            Xn[0][2] = hg * X[0][2] + hgi * c02;
            Xn[1][0] = hg * X[1][0] + hgi * c10;
            Xn[1][1] = hg * X[1][1] + hgi * c11;
            Xn[1][2] = hg * X[1][2] + hgi * c12;
            Xn[2][0] = hg * X[2][0] + hgi * c20;
            Xn[2][1] = hg * X[2][1] + hgi * c21;
            Xn[2][2] = hg * X[2][2] + hgi * c22;
#pragma unroll
            for (int i = 0; i < 3; ++i)
#pragma unroll
                for (int j = 0; j < 3; ++j) X[i][j] = Xn[i][j];
        }
#pragma unroll
        for (int i = 0; i < 3; ++i)
#pragma unroll
            for (int j = 0; j < 3; ++j) Rt[i * 3 + j] = X[i][j];
#pragma unroll
        for (int j = 0; j < 3; ++j)
            Rt[9 + j] = cA[j] - (cB[0] * X[0][j] + cB[1] * X[1][j] + cB[2] * X[2][j])
                      + y_tr[b * 3 + j];
    }
    __syncthreads();

    const float x0 = Bx[0], x1 = Bx[1], x2 = Bx[2];
#pragma unroll
    for (int j = 0; j < 3; ++j) {
        out[row * 3 + j] = x0 * Rt[j] + x1 * Rt[3 + j] + x2 * Rt[6 + j] + Rt[9 + j];
    }
}

// ---------------------------------------------------------------------------
extern "C" void kernel_launch(void* const* d_in, const int* in_sizes, int n_in,
                              void* d_out, int out_size, void* d_ws, size_t ws_size,
                              hipStream_t stream)
{
    const float* x_orig       = (const float*)d_in[0];
    const float* y_orig       = (const float*)d_in[1];
    const float* lin_in_w     = (const float*)d_in[2];
    const float* lin_in_b     = (const float*)d_in[3];
    const float* lin_coords_w = (const float*)d_in[4];
    const float* lin_coords_b = (const float*)d_in[5];
    const float* attn_w_in    = (const float*)d_in[6];
    const float* attn_b_in    = (const float*)d_in[7];
    const float* attn_w_out   = (const float*)d_in[8];
    const float* attn_b_out   = (const float*)d_in[9];
    const float* af_w_in      = (const float*)d_in[10];
    const float* af_b_in      = (const float*)d_in[11];
    const float* af_w_out     = (const float*)d_in[12];
    const float* af_b_out     = (const float*)d_in[13];
    const float* ccf_w_in     = (const float*)d_in[14];
    const float* ccf_b_in     = (const float*)d_in[15];
    const float* ccf_w_out    = (const float*)d_in[16];
    const float* ccf_b_out    = (const float*)d_in[17];
    const float* cr_w_in      = (const float*)d_in[18];
    const float* cr_b_in      = (const float*)d_in[19];
    const float* cr_w_out     = (const float*)d_in[20];
    const float* cr_b_out     = (const float*)d_in[21];
    const float* lin_out_w    = (const float*)d_in[22];
    const float* lin_out_b    = (const float*)d_in[23];

    float* ws = (float*)d_ws;
    const size_t BN3 = (size_t)NB * NN * 3;
    const size_t BNE = (size_t)NB * NN * NE;

    float* x_c   = ws;                 // BN3
    float* y_tr  = x_c + BN3;          // 192
    float* A     = y_tr + 192;         // BNE (xi)
    float* B     = A + BNE;            // BNE (yi)
    float* C     = B + BNE;            // BNE (xi_feat)
    float* D     = C + BNE;            // BNE (yi_feat)
    float* E0    = D + BNE;            // BNE
    float* E1    = E0 + BNE;
    float* E2    = E1 + BNE;
    float* E3    = E2 + BNE;

    const size_t batch_floats = BN3 + 192 + 8 * BNE + NB * (15 + 9 + 3);
    const bool batched = ws_size >= batch_floats * sizeof(float);

    prep_kernel<<<NB, 512, 0, stream>>>(x_orig, y_orig, lin_in_w, lin_in_b,
                                        lin_coords_w, lin_coords_b,
                                        x_c, y_tr, A, B, C, D);

    auto set_op = [](MhaBatchArgs& a, int i, const float* q, const float* kv,
                     const float* wi, const float* bi,
                     const float* wo, const float* bo, float* o) {
        a.q[i] = q; a.kv[i] = kv; a.wi[i] = wi; a.bi[i] = bi;
        a.wo[i] = wo; a.bo[i] = bo; a.out[i] = o;
    };

    if (batched) {
        MhaBatchArgs a1{};
        set_op(a1, 0, C, C, af_w_in, af_b_in, af_w_out, af_b_out, E0);   // xf2
        set_op(a1, 1, D, D, af_w_in, af_b_in, af_w_out, af_b_out, E1);   // yf2
        set_op(a1, 2, A, A, attn_w_in, attn_b_in, attn_w_out, attn_b_out, E2); // xi2
        set_op(a1, 3, B, B, attn_w_in, attn_b_in, attn_w_out, attn_b_out, E3); // yi2
        attn_mfma_kernel<<<4 * 512, 512, 0, stream>>>(a1);
        MhaBatchArgs a2{};
        set_op(a2, 0, E2, E0, ccf_w_in, ccf_b_in, ccf_w_out, ccf_b_out, A); // cross_x
        set_op(a2, 1, E3, E1, ccf_w_in, ccf_b_in, ccf_w_out, ccf_b_out, B); // cross_y
        attn_mfma_kernel<<<2 * 512, 512, 0, stream>>>(a2);
        MhaBatchArgs a3{};
        set_op(a3, 0, A, B, cr_w_in, cr_b_in, cr_w_out, cr_b_out, C);       // cross
        attn_mfma_kernel<<<512, 512, 0, stream>>>(a3);
        kabsch_fused_kernel<<<NB, 512, 0, stream>>>(C, lin_out_w, lin_out_b,
                                                    x_c, y_tr, (float*)d_out);
    } else {
        auto mha1 = [&](const float* q, const float* kv,
                        const float* wi, const float* bi,
                        const float* wo, const float* bo, float* o) {
            MhaBatchArgs a{};
            set_op(a, 0, q, kv, wi, bi, wo, bo, o);
            attn_mfma_kernel<<<512, 512, 0, stream>>>(a);
        };
        mha1(C, C, af_w_in, af_b_in, af_w_out, af_b_out, E0);     // xf2 = E0
        mha1(D, D, af_w_in, af_b_in, af_w_out, af_b_out, C);      // yf2 = C
        mha1(A, A, attn_w_in, attn_b_in, attn_w_out, attn_b_out, D); // xi2 = D
        mha1(B, B, attn_w_in, attn_b_in, attn_w_out, attn_b_out, A); // yi2 = A
        mha1(D, E0, ccf_w_in, ccf_b_in, ccf_w_out, ccf_b_out, B); // cross_x = B
        mha1(A, C, ccf_w_in, ccf_b_in, ccf_w_out, ccf_b_out, E0); // cross_y = E0
        mha1(B, E0, cr_w_in, cr_b_in, cr_w_out, cr_b_out, C);     // cross = C
        kabsch_fused_kernel<<<NB, 512, 0, stream>>>(C, lin_out_w, lin_out_b,
                                                    x_c, y_tr, (float*)d_out);
    }
}

// Round 16
// 95.932 us; speedup vs baseline: 1.0969x; 1.0969x over previous
//
#include <hip/hip_runtime.h>
#include <hip/hip_fp16.h>
#include <math.h>

#define NB 64    // batches
#define NN 512   // sequence length
#define NE 12    // embed dim
#define NH 4     // heads
#define NF 13    // features (F-3)

typedef __attribute__((ext_vector_type(4))) _Float16 f16x4;
typedef __attribute__((ext_vector_type(4))) float    f32x4;

__device__ inline float wave_reduce_add(float v) {
#pragma unroll
    for (int off = 1; off < 64; off <<= 1) v += __shfl_xor(v, off);
    return v;
}

__device__ inline unsigned h2u(__half2 h) { union { __half2 h; unsigned u; } c; c.h = h; return c.u; }

union HU { f16x4 h; uint2 u; };

// ---------------------------------------------------------------------------
// prep: center coords, compute y_translate, project coords->E and feats->E
// ---------------------------------------------------------------------------
__global__ __launch_bounds__(512) void prep_kernel(
    const float* __restrict__ x_orig, const float* __restrict__ y_orig,
    const float* __restrict__ lin_in_w, const float* __restrict__ lin_in_b,
    const float* __restrict__ lin_coords_w, const float* __restrict__ lin_coords_b,
    float* __restrict__ x_c, float* __restrict__ y_tr,
    float* __restrict__ xi, float* __restrict__ yi,
    float* __restrict__ xi_feat, float* __restrict__ yi_feat)
{
    const int b = blockIdx.x;
    const int n = threadIdx.x;
    const size_t row = (size_t)b * NN + n;
    const float* xr = x_orig + row * 16;
    const float* yr = y_orig + row * 16;
    float xv[16], yv[16];
#pragma unroll
    for (int i = 0; i < 16; ++i) { xv[i] = xr[i]; yv[i] = yr[i]; }

    __shared__ float part[8][6];
    const int wid = n >> 6, lane = n & 63;
    float r0 = wave_reduce_add(xv[0]);
    float r1 = wave_reduce_add(xv[1]);
    float r2 = wave_reduce_add(xv[2]);
    float r3 = wave_reduce_add(yv[0]);
    float r4 = wave_reduce_add(yv[1]);
    float r5 = wave_reduce_add(yv[2]);
    if (lane == 0) {
        part[wid][0] = r0; part[wid][1] = r1; part[wid][2] = r2;
        part[wid][3] = r3; part[wid][4] = r4; part[wid][5] = r5;
    }
    __syncthreads();
    float xm[3], ym[3];
#pragma unroll
    for (int c = 0; c < 3; ++c) {
        float sx = 0.f, sy = 0.f;
#pragma unroll
        for (int w = 0; w < 8; ++w) { sx += part[w][c]; sy += part[w][3 + c]; }
        xm[c] = sx * (1.0f / NN); ym[c] = sy * (1.0f / NN);
    }

    float xc[3], yc[3];
#pragma unroll
    for (int c = 0; c < 3; ++c) { xc[c] = xv[c] - xm[c]; yc[c] = yv[c] - ym[c]; }

#pragma unroll
    for (int c = 0; c < 3; ++c) x_c[row * 3 + c] = xc[c];
    if (n < 3) y_tr[b * 3 + n] = ym[n];

#pragma unroll
    for (int e = 0; e < NE; ++e) {
        float sx = lin_coords_b[e], sy = lin_coords_b[e];
#pragma unroll
        for (int c = 0; c < 3; ++c) {
            sx += xc[c] * lin_coords_w[e * 3 + c];
            sy += yc[c] * lin_coords_w[e * 3 + c];
        }
        xi[row * NE + e] = sx;
        yi[row * NE + e] = sy;
    }
#pragma unroll
    for (int e = 0; e < NE; ++e) {
        float sx = lin_in_b[e], sy = lin_in_b[e];
#pragma unroll
        for (int f = 0; f < NF; ++f) {
            sx += xv[3 + f] * lin_in_w[e * NF + f];
            sy += yv[3 + f] * lin_in_w[e * NF + f];
        }
        xi_feat[row * NE + e] = sx;
        yi_feat[row * NE + e] = sy;
    }
}

// ---------------------------------------------------------------------------
// MFMA fused MHA (batched over up to 4 independent ops per dispatch)
// per op: 256 blocks = (b, 128-query quarter); 512 threads = 8 waves.
// wave w: head h = w>>1, 64-q half q64 = w&1, owns 4 q-tiles of 16.
// S-tile = mfma_16x16x16_f16(A=K, B=Q) -> exp2 in-register -> fragment
// feeds PV mfma(A=V^T, B=P) directly (D layout == B-operand layout,
// HW-verified r10). V^T row 3 = ones -> denominator in acc row 3.
// r16: = r13 (best config: 128q blocks, f32 att, 46KB LDS, 3 blk/CU)
// + T5 s_setprio(1) around the main loop (catalog: +4-7% on attn when
// co-resident waves are phase-drifted; our 6 waves/SIMD qualify).
// [r15 lesson: 64q blocks double staging reads (FETCH 12.4->24.6MB)
// for no overlap gain; r14 lesson: explicit pipeline + branch regresses.]
// ---------------------------------------------------------------------------
struct MhaBatchArgs {
    const float* q[4];
    const float* kv[4];
    const float* wi[4];
    const float* bi[4];
    const float* wo[4];
    const float* bo[4];
    float*       out[4];
};

__global__ __launch_bounds__(512) void attn_mfma_kernel(MhaBatchArgs args)
{
    const int op    = blockIdx.x >> 8;
    const int bid   = blockIdx.x & 255;
    const int b     = bid >> 2;
    const int qbase = (bid & 3) << 7;    // quarter * 128
    const int tid   = threadIdx.x;
    const int lane  = tid & 63;
    const int w     = tid >> 6;
    const int h     = w >> 1;            // head
    const int q64   = w & 1;             // which 64-q half of the quarter

    const float* __restrict__ qin   = args.q[op];
    const float* __restrict__ kvin  = args.kv[op];
    const float* __restrict__ w_in  = args.wi[op];
    const float* __restrict__ b_in  = args.bi[op];
    const float* __restrict__ w_out = args.wo[op];
    const float* __restrict__ b_out = args.bo[op];
    float* __restrict__ out = args.out[op];

    __shared__ __align__(16) __half K_lds[NH][NN][4];   // (kx,ky,kz,0) 16,384 B
    __shared__ __align__(16) __half V_lds[NH][4][528];  // rows vx,vy,vz,1 16,896 B
    __shared__ __align__(16) uint2  qbuf[128][NH];      // Q f16 staging 4,096 B
    __shared__ __align__(16) float  att[128][NE];       // 6,144 B
    __shared__ float  w_lds[36][NE];
    __shared__ float  b_lds[36];
    __shared__ __align__(16) float4 wo4[NE][3];
    __shared__ float  bo_lds[NE];

    if (tid < 432) w_lds[tid / NE][tid % NE] = w_in[tid];
    if (tid < 36)  b_lds[tid] = b_in[tid];
    if (tid < 144) ((float*)wo4)[tid] = w_out[tid];
    if (tid < NE)  bo_lds[tid] = b_out[tid];
    __syncthreads();

    // ---- stage K,V (thread = key, all heads), f16 ----
    {
        const int n = tid;
        const float4* kvrow = (const float4*)(kvin + ((size_t)b * NN + n) * NE);
        float4 r0 = kvrow[0], r1 = kvrow[1], r2 = kvrow[2];
        float x[NE] = { r0.x, r0.y, r0.z, r0.w, r1.x, r1.y, r1.z, r1.w,
                        r2.x, r2.y, r2.z, r2.w };
#pragma unroll
        for (int hh = 0; hh < NH; ++hh) {
            float sk[3], sv[3];
#pragma unroll
            for (int c = 0; c < 3; ++c) {
                const int rk = NE + hh * 3 + c;
                const int rv = 2 * NE + hh * 3 + c;
                float a = b_lds[rk], v = b_lds[rv];
#pragma unroll
                for (int e = 0; e < NE; ++e) {
                    a += x[e] * w_lds[rk][e];
                    v += x[e] * w_lds[rv][e];
                }
                sk[c] = a; sv[c] = v;
            }
            uint2 kk;
            kk.x = h2u(__floats2half2_rn(sk[0], sk[1]));
            kk.y = h2u(__floats2half2_rn(sk[2], 0.0f));
            *(uint2*)&K_lds[hh][n][0] = kk;
            V_lds[hh][0][n] = __float2half(sv[0]);
            V_lds[hh][1][n] = __float2half(sv[1]);
            V_lds[hh][2][n] = __float2half(sv[2]);
            V_lds[hh][3][n] = __float2half(1.0f);
        }
    }
    // ---- stage Q (thread = (q, head)); scale = log2e/sqrt3 folded ----
    {
        const float scale = 0.83294037f;   // log2(e)/sqrt(3)
        const int q = tid >> 2, hh = tid & 3;
        const float4* qrow = (const float4*)(qin + ((size_t)b * NN + qbase + q) * NE);
        float4 r0 = qrow[0], r1 = qrow[1], r2 = qrow[2];
        float x[NE] = { r0.x, r0.y, r0.z, r0.w, r1.x, r1.y, r1.z, r1.w,
                        r2.x, r2.y, r2.z, r2.w };
        float qc[3];
#pragma unroll
        for (int c = 0; c < 3; ++c) {
            const int rq = hh * 3 + c;
            float s = b_lds[rq];
#pragma unroll
            for (int e = 0; e < NE; ++e) s += x[e] * w_lds[rq][e];
            qc[c] = s * scale;
        }
        uint2 qq;
        qq.x = h2u(__floats2half2_rn(qc[0], qc[1]));
        qq.y = h2u(__floats2half2_rn(qc[2], 0.0f));
        qbuf[q][hh] = qq;
    }
    __syncthreads();

    // ---- per-wave Q B-fragments (4 q-tiles); rows d>=3 MUST be zero ----
    const int ql = lane & 15;
    const int g  = lane >> 4;
    f16x4 qf[4];
#pragma unroll
    for (int j = 0; j < 4; ++j) {
        HU c;
        c.u = qbuf[q64 * 64 + j * 16 + ql][h];
        if (lane >= 16) { c.u.x = 0u; c.u.y = 0u; }   // zero d>=4 rows
        qf[j] = c.h;
    }
    f32x4 acc[4];
#pragma unroll
    for (int j = 0; j < 4; ++j) acc[j] = (f32x4){0.f, 0.f, 0.f, 0.f};

    const f32x4 zero4 = {0.f, 0.f, 0.f, 0.f};

    // ---- main loop: 32 k-tiles of 16 keys; setprio favors this wave's
    //      MFMA+exp cluster while other waves are staging/merging (T5) ----
    __builtin_amdgcn_s_setprio(1);
    for (int ks = 0; ks < 32; ++ks) {
        HU kc; kc.u = *(const uint2*)&K_lds[h][ks * 16 + ql][0];          // A=K
        HU vc; vc.u = *(const uint2*)&V_lds[h][lane & 3][ks * 16 + 4 * g]; // A=V^T
#pragma unroll
        for (int j = 0; j < 4; ++j) {
            f32x4 s = __builtin_amdgcn_mfma_f32_16x16x16f16(kc.h, qf[j], zero4, 0, 0, 0);
            float p0 = __builtin_amdgcn_exp2f(s[0]);
            float p1 = __builtin_amdgcn_exp2f(s[1]);
            float p2 = __builtin_amdgcn_exp2f(s[2]);
            float p3 = __builtin_amdgcn_exp2f(s[3]);
            HU pc;
            pc.u.x = h2u(__floats2half2_rn(p0, p1));
            pc.u.y = h2u(__floats2half2_rn(p2, p3));
            acc[j] = __builtin_amdgcn_mfma_f32_16x16x16f16(vc.h, pc.h, acc[j], 0, 0, 0);
        }
    }
    __builtin_amdgcn_s_setprio(0);

    // ---- epilogue: lanes 0-15 hold rows 0-3 = (o0,o1,o2,l) per q ----
    if (lane < 16) {
#pragma unroll
        for (int j = 0; j < 4; ++j) {
            const int qloc = q64 * 64 + j * 16 + lane;
            const float inv = 1.0f / acc[j][3];
            att[qloc][h * 3 + 0] = acc[j][0] * inv;
            att[qloc][h * 3 + 1] = acc[j][1] * inv;
            att[qloc][h * 3 + 2] = acc[j][2] * inv;
        }
    }
    __syncthreads();

    // ---- fused output projection: 128 q x 12 outputs ----
    for (int idx = tid; idx < 128 * NE; idx += 512) {
        const int qq = idx / NE, o = idx % NE;
        const float4* a4 = (const float4*)&att[qq][0];
        float4 a0 = a4[0], a1 = a4[1], a2 = a4[2];
        float4 w0 = wo4[o][0], w1 = wo4[o][1], w2 = wo4[o][2];
        float s = bo_lds[o]
                + a0.x * w0.x + a0.y * w0.y + a0.z * w0.z + a0.w * w0.w
                + a1.x * w1.x + a1.y * w1.y + a1.z * w1.z + a1.w * w1.w
                + a2.x * w2.x + a2.y * w2.y + a2.z * w2.z + a2.w * w2.w;
        out[((size_t)b * NN + qbase + qq) * NE + o] = s;
    }
}

// ---------------------------------------------------------------------------
// fused kabsch: coords-proj + stats reduce + Newton polar solve + final
// transform, one kernel, one block per batch.
// ---------------------------------------------------------------------------
__global__ __launch_bounds__(512) void kabsch_fused_kernel(
    const float* __restrict__ cross, const float* __restrict__ lin_out_w,
    const float* __restrict__ lin_out_b, const float* __restrict__ x_c,
    const float* __restrict__ y_tr, float* __restrict__ out)
{
    const int b = blockIdx.x;
    const int n = threadIdx.x;
    const size_t row = (size_t)b * NN + n;
    const float* xr = cross + row * NE;
    float xin[NE];
#pragma unroll
    for (int e = 0; e < NE; ++e) xin[e] = xr[e];
    float cd[3];
#pragma unroll
    for (int o = 0; o < 3; ++o) {
        float s = lin_out_b[o];
#pragma unroll
        for (int e = 0; e < NE; ++e) s += xin[e] * lin_out_w[o * NE + e];
        cd[o] = s;
    }
    float Bx[3], A[3];
#pragma unroll
    for (int c = 0; c < 3; ++c) { Bx[c] = x_c[row * 3 + c]; A[c] = cd[c] + Bx[c]; }

    float vals[15];
#pragma unroll
    for (int i = 0; i < 3; ++i)
#pragma unroll
        for (int j = 0; j < 3; ++j) vals[i * 3 + j] = Bx[i] * A[j];
#pragma unroll
    for (int i = 0; i < 3; ++i) { vals[9 + i] = Bx[i]; vals[12 + i] = A[i]; }

    __shared__ float part[8][15];
    __shared__ float Rt[12];           // R[9], t[3] (t includes y_tr)
    const int wid = n >> 6, lane = n & 63;
#pragma unroll
    for (int t = 0; t < 15; ++t) {
        float r = wave_reduce_add(vals[t]);
        if (lane == 0) part[wid][t] = r;
    }
    __syncthreads();

    if (n == 0) {
        float s[15];
#pragma unroll
        for (int t = 0; t < 15; ++t) {
            float acc = 0.f;
#pragma unroll
            for (int ww = 0; ww < 8; ++ww) acc += part[ww][t];
            s[t] = acc;
        }
        float cB[3], cA[3];
#pragma unroll
        for (int j = 0; j < 3; ++j) { cB[j] = s[9 + j] * (1.0f / NN); cA[j] = s[12 + j] * (1.0f / NN); }
        float X[3][3];
#pragma unroll
        for (int i = 0; i < 3; ++i)
#pragma unroll
            for (int j = 0; j < 3; ++j) X[i][j] = s[i * 3 + j] - s[9 + i] * cA[j];

        for (int it = 0; it < 14; ++it) {
            float c00 =  X[1][1] * X[2][2] - X[1][2] * X[2][1];
            float c01 = -(X[1][0] * X[2][2] - X[1][2] * X[2][0]);
            float c02 =  X[1][0] * X[2][1] - X[1][1] * X[2][0];
            float c10 = -(X[0][1] * X[2][2] - X[0][2] * X[2][1]);
            float c11 =  X[0][0] * X[2][2] - X[0][2] * X[2][0];
            float c12 = -(X[0][0] * X[2][1] - X[0][1] * X[2][0]);
            float c20 =  X[0][1] * X[1][2] - X[0][2] * X[1][1];
            float c21 = -(X[0][0] * X[1][2] - X[0][2] * X[1][0]);
            float c22 =  X[0][0] * X[1][1] - X[0][1] * X[1][0];
            float det = X[0][0] * c00 + X[0][1] * c01 + X[0][2] * c02;
            float ad = fabsf(det);
            float g  = (ad > 1e-30f) ? 1.0f / cbrtf(ad) : 1.0f;
            float hg  = 0.5f * g;
            float hgi = 0.5f / (g * det);
            float Xn[3][3];
            Xn[0][0] = hg * X[0][0] + hgi * c00;
            Xn[0][1] = hg * X[0][1] + hgi * c01;
            Xn[0][2] = hg * X[0][2] + hgi * c02;
            Xn[1][0] = hg * X[1][0] + hgi * c10;
            Xn[1][1] = hg * X[1][1] + hgi * c11;
            Xn[1][2] = hg * X[1][2] + hgi * c12;
            Xn[2][0] = hg * X[2][0] + hgi * c20;
            Xn[2][1] = hg * X[2][1] + hgi * c21;
            Xn[2][2] = hg * X[2][2] + hgi * c22;
#pragma unroll
            for (int i = 0; i < 3; ++i)
#pragma unroll
                for (int j = 0; j < 3; ++j) X[i][j] = Xn[i][j];
        }
#pragma unroll
        for (int i = 0; i < 3; ++i)
#pragma unroll
            for (int j = 0; j < 3; ++j) Rt[i * 3 + j] = X[i][j];
#pragma unroll
        for (int j = 0; j < 3; ++j)
            Rt[9 + j] = cA[j] - (cB[0] * X[0][j] + cB[1] * X[1][j] + cB[2] * X[2][j])
                      + y_tr[b * 3 + j];
    }
    __syncthreads();

    const float x0 = Bx[0], x1 = Bx[1], x2 = Bx[2];
#pragma unroll
    for (int j = 0; j < 3; ++j) {
        out[row * 3 + j] = x0 * Rt[j] + x1 * Rt[3 + j] + x2 * Rt[6 + j] + Rt[9 + j];
    }
}

// ---------------------------------------------------------------------------
extern "C" void kernel_launch(void* const* d_in, const int* in_sizes, int n_in,
                              void* d_out, int out_size, void* d_ws, size_t ws_size,
                              hipStream_t stream)
{
    const float* x_orig       = (const float*)d_in[0];
    const float* y_orig       = (const float*)d_in[1];
    const float* lin_in_w     = (const float*)d_in[2];
    const float* lin_in_b     = (const float*)d_in[3];
    const float* lin_coords_w = (const float*)d_in[4];
    const float* lin_coords_b = (const float*)d_in[5];
    const float* attn_w_in    = (const float*)d_in[6];
    const float* attn_b_in    = (const float*)d_in[7];
    const float* attn_w_out   = (const float*)d_in[8];
    const float* attn_b_out   = (const float*)d_in[9];
    const float* af_w_in      = (const float*)d_in[10];
    const float* af_b_in      = (const float*)d_in[11];
    const float* af_w_out     = (const float*)d_in[12];
    const float* af_b_out     = (const float*)d_in[13];
    const float* ccf_w_in     = (const float*)d_in[14];
    const float* ccf_b_in     = (const float*)d_in[15];
    const float* ccf_w_out    = (const float*)d_in[16];
    const float* ccf_b_out    = (const float*)d_in[17];
    const float* cr_w_in      = (const float*)d_in[18];
    const float* cr_b_in      = (const float*)d_in[19];
    const float* cr_w_out     = (const float*)d_in[20];
    const float* cr_b_out     = (const float*)d_in[21];
    const float* lin_out_w    = (const float*)d_in[22];
    const float* lin_out_b    = (const float*)d_in[23];

    float* ws = (float*)d_ws;
    const size_t BN3 = (size_t)NB * NN * 3;
    const size_t BNE = (size_t)NB * NN * NE;

    float* x_c   = ws;                 // BN3
    float* y_tr  = x_c + BN3;          // 192
    float* A     = y_tr + 192;         // BNE (xi)
    float* B     = A + BNE;            // BNE (yi)
    float* C     = B + BNE;            // BNE (xi_feat)
    float* D     = C + BNE;            // BNE (yi_feat)
    float* E0    = D + BNE;            // BNE
    float* E1    = E0 + BNE;
    float* E2    = E1 + BNE;
    float* E3    = E2 + BNE;

    const size_t batch_floats = BN3 + 192 + 8 * BNE + NB * (15 + 9 + 3);
    const bool batched = ws_size >= batch_floats * sizeof(float);

    prep_kernel<<<NB, 512, 0, stream>>>(x_orig, y_orig, lin_in_w, lin_in_b,
                                        lin_coords_w, lin_coords_b,
                                        x_c, y_tr, A, B, C, D);

    auto set_op = [](MhaBatchArgs& a, int i, const float* q, const float* kv,
                     const float* wi, const float* bi,
                     const float* wo, const float* bo, float* o) {
        a.q[i] = q; a.kv[i] = kv; a.wi[i] = wi; a.bi[i] = bi;
        a.wo[i] = wo; a.bo[i] = bo; a.out[i] = o;
    };

    if (batched) {
        MhaBatchArgs a1{};
        set_op(a1, 0, C, C, af_w_in, af_b_in, af_w_out, af_b_out, E0);   // xf2
        set_op(a1, 1, D, D, af_w_in, af_b_in, af_w_out, af_b_out, E1);   // yf2
        set_op(a1, 2, A, A, attn_w_in, attn_b_in, attn_w_out, attn_b_out, E2); // xi2
        set_op(a1, 3, B, B, attn_w_in, attn_b_in, attn_w_out, attn_b_out, E3); // yi2
        attn_mfma_kernel<<<4 * 256, 512, 0, stream>>>(a1);
        MhaBatchArgs a2{};
        set_op(a2, 0, E2, E0, ccf_w_in, ccf_b_in, ccf_w_out, ccf_b_out, A); // cross_x
        set_op(a2, 1, E3, E1, ccf_w_in, ccf_b_in, ccf_w_out, ccf_b_out, B); // cross_y
        attn_mfma_kernel<<<2 * 256, 512, 0, stream>>>(a2);
        MhaBatchArgs a3{};
        set_op(a3, 0, A, B, cr_w_in, cr_b_in, cr_w_out, cr_b_out, C);       // cross
        attn_mfma_kernel<<<256, 512, 0, stream>>>(a3);
        kabsch_fused_kernel<<<NB, 512, 0, stream>>>(C, lin_out_w, lin_out_b,
                                                    x_c, y_tr, (float*)d_out);
    } else {
        auto mha1 = [&](const float* q, const float* kv,
                        const float* wi, const float* bi,
                        const float* wo, const float* bo, float* o) {
            MhaBatchArgs a{};
            set_op(a, 0, q, kv, wi, bi, wo, bo, o);
            attn_mfma_kernel<<<256, 512, 0, stream>>>(a);
        };
        mha1(C, C, af_w_in, af_b_in, af_w_out, af_b_out, E0);     // xf2 = E0
        mha1(D, D, af_w_in, af_b_in, af_w_out, af_b_out, C);      // yf2 = C
        mha1(A, A, attn_w_in, attn_b_in, attn_w_out, attn_b_out, D); // xi2 = D
        mha1(B, B, attn_w_in, attn_b_in, attn_w_out, attn_b_out, A); // yi2 = A
        mha1(D, E0, ccf_w_in, ccf_b_in, ccf_w_out, ccf_b_out, B); // cross_x = B
        mha1(A, C, ccf_w_in, ccf_b_in, ccf_w_out, ccf_b_out, E0); // cross_y = E0
        mha1(B, E0, cr_w_in, cr_b_in, cr_w_out, cr_b_out, C);     // cross = C
        kabsch_fused_kernel<<<NB, 512, 0, stream>>>(C, lin_out_w, lin_out_b,
                                                    x_c, y_tr, (float*)d_out);
    }
}